// Round 7
// baseline (274.242 us; speedup 1.0000x reference)
//
#include <hip/hip_runtime.h>
#include <hip/hip_bf16.h>
#include <math.h>

#define NB 256
#define SS 512
#define LL 128

typedef short bf16x8 __attribute__((ext_vector_type(8)));
typedef float f32x4 __attribute__((ext_vector_type(4)));

template <int P>
__device__ __forceinline__ float swzf(float x) {
    return __int_as_float(__builtin_amdgcn_ds_swizzle(__float_as_int(x), P));
}
__device__ __forceinline__ short f2bf(float f) {
    __hip_bfloat16 h = __float2bfloat16(f);
    short s;
    __builtin_memcpy(&s, &h, 2);
    return s;
}

// One block = 64 threads = ONE wave = one chain (fwd or bwd) of one batch.
// grid = 512 (blocks 0..255 fwd, 256..511 bwd), 2 blocks/CU. Zero barriers:
// same-wave DS ops are in-order, block-private LDS.
// NO global loads in the steady-state loop: features are staged fp32 into a
// 2x8KB LDS double buffer in 16-round chunks. Chunk burst = 8 dwordx4 loads
// into 32 staging VGPRs issued 16 rounds before their 8 ds_write_b128 --
// exactly one localized vmcnt wait per 16 rounds.
// Round critical path: publish u image (2 cvt + 2 ds_write_b16) -> 4
// broadcast ds_read_b128 -> per N-tile two independent 2-deep MFMA chains +
// 1 v_add (only C reg0 consumed) -> 8 cndmask. Off-path: 8 ds_read_b32
// feature reads + exp(f) one round ahead, mask read one round ahead, exact
// power-of-2 rescale every 8 rounds (wave-local, bitwise-identical lanes).
__global__ __launch_bounds__(64, 1) void crf_chain_kernel(
    const float* __restrict__ feats,    // (B,S,L)
    const float* __restrict__ start_t,  // (L)
    const float* __restrict__ end_t,    // (L)
    const float* __restrict__ trans,    // (L,L)
    const int* __restrict__ mask,       // (B,S)
    const int* __restrict__ labels,     // (B,S)
    float* __restrict__ ws)             // av[32768] bv[32768] eF[256] eB[256] ln[256]
{
    const int bid = blockIdx.x;
    const int b = bid & 255;
    const int isB = bid >> 8;   // 0 = fwd chain, 1 = bwd chain
    const int l = threadIdx.x;  // 0..63
    const int l15 = l & 15;
    const int g = l >> 4;       // k-quad

    __shared__ __align__(16) short img[LL];       // u image, bf16
    __shared__ __align__(16) float fbuf[2][16 * LL]; // feature dbuf, 16 KB
    __shared__ int lmk[256];                      // mask by ROUND index

    const float* fb = feats + (size_t)b * SS * LL;
    const int* mk = mask + b * SS;

    // ---- mask-by-round staging (single wave, in-order DS, no barrier) ----
#pragma unroll
    for (int q = 0; q < 4; ++q) {
        const int r = l + 64 * q;
        lmk[r] = isB ? mk[511 - r] : ((r < 255) ? mk[r + 1] : 0);
    }

    // ---- exp(transition) B-fragments: Bf[kt][nt], 32 frags ----
    // fwd: B[k][n] = exp(T[k][n]); bwd: exp(T[n][k]) (= T^T)
    bf16x8 Bf[4][8];
#pragma unroll
    for (int kt = 0; kt < 4; ++kt) {
#pragma unroll
        for (int nt = 0; nt < 8; ++nt) {
            const int n = 16 * nt + l15;
            bf16x8 fr;
#pragma unroll
            for (int j = 0; j < 8; ++j) {
                const int k = 32 * kt + 8 * g + j;
                const float v = isB ? trans[n * LL + k] : trans[k * LL + n];
                fr[j] = f2bf(__expf(v));
            }
            Bf[kt][nt] = fr;
        }
    }

    // ---- chain state: x[nt] = u[16*nt + l15], duplicated across g ----
    float x[8];
#pragma unroll
    for (int nt = 0; nt < 8; ++nt) {
        const int n = 16 * nt + l15;
        x[nt] = isB ? __expf(end_t[n]) : __expf(start_t[n] + fb[n]);
    }
    int eacc = 0;

    // ---- chunk staging machinery: chunk c = rounds 16c..16c+15 ----
    // fwd round r -> t = r+1 (chunk rows t=16c+1..16c+16, slot = row_rel)
    // bwd round r -> t = 511-r (chunk rows t=511-16c-row_rel, slot = row_rel)
    float4 stg[8];
    auto issue_chunk = [&](int c) {
        const int base_t = isB ? (511 - 16 * c) : (16 * c + 1);
#pragma unroll
        for (int q = 0; q < 8; ++q) {
            const int v = l + 64 * q;        // float4 index in [0,512)
            const int row_rel = v >> 5;      // 0..15
            const int pos4 = v & 31;
            const int t = isB ? (base_t - row_rel) : (base_t + row_rel);
            stg[q] = *(const float4*)(fb + (size_t)t * LL + 4 * pos4);
        }
    };
    auto write_chunk = [&](int c) {
        float* dst = fbuf[c & 1];
#pragma unroll
        for (int q = 0; q < 8; ++q) {
            const int v = l + 64 * q;
            const int row_rel = v >> 5;
            const int pos4 = v & 31;
            *(float4*)(dst + row_rel * LL + 4 * pos4) = stg[q];
        }
    };

    // prologue: chunks 0 and 1 resident, chunk 2 in flight
    issue_chunk(0);
    write_chunk(0);
    issue_chunk(1);
    write_chunk(1);
    issue_chunk(2);

    // round-0 feature + mask prefetch (from buf 0) and exp
    float fn[8], ef[8], efn[8];
#pragma unroll
    for (int nt = 0; nt < 8; ++nt) fn[nt] = fbuf[0][16 * nt + l15];
#pragma unroll
    for (int nt = 0; nt < 8; ++nt) ef[nt] = __expf(fn[nt]);
    int mt_c = lmk[0];

    const f32x4 zf = {0.f, 0.f, 0.f, 0.f};

    for (int it = 0; it < 32; ++it) {
        // chunk boundary (r = 8*it with it even): write chunk c+1 (its loads
        // were issued 16 rounds ago), then issue chunk c+2's loads.
        if ((it & 1) == 0) {
            const int c = it >> 1;
            if (c >= 1 && c <= 14) {
                write_chunk(c + 1);   // one vmcnt wait, data long-resident
                if (c <= 13) issue_chunk(c + 2);
            }
        }
#pragma unroll
        for (int h = 0; h < 8; ++h) {
            const int r = 8 * it + h;

            // ---- publish u image: quad g writes N-tiles 2g, 2g+1 ----
#pragma unroll
            for (int gg = 0; gg < 2; ++gg) {
                const int nt = 2 * g + gg;
                const float pub = isB ? ef[nt] * x[nt] : x[nt];
                img[16 * nt + l15] = f2bf(pub);
            }

            // ---- read A-frags (broadcast b128, same-wave in-order DS) ----
            bf16x8 a[4];
#pragma unroll
            for (int kt = 0; kt < 4; ++kt)
                __builtin_memcpy(&a[kt], &img[32 * kt + 8 * g], 16);

            // ---- next round's feature (LDS) + exp + mask (off path) ----
            const int rn = (r < 255) ? (r + 1) : 255;
            const float* frow = &fbuf[(rn >> 4) & 1][(rn & 15) * LL];
#pragma unroll
            for (int nt = 0; nt < 8; ++nt) fn[nt] = frow[16 * nt + l15];
            const int mt_n = lmk[rn];
#pragma unroll
            for (int nt = 0; nt < 8; ++nt) efn[nt] = __expf(fn[nt]);

            // ---- MFMA: per N-tile, two independent 2-deep chains + add ----
            float cres[8];
#pragma unroll
            for (int nt = 0; nt < 8; ++nt) {
                f32x4 c1 = __builtin_amdgcn_mfma_f32_16x16x32_bf16(a[0], Bf[0][nt], zf, 0, 0, 0);
                f32x4 c2 = __builtin_amdgcn_mfma_f32_16x16x32_bf16(a[2], Bf[2][nt], zf, 0, 0, 0);
                c1 = __builtin_amdgcn_mfma_f32_16x16x32_bf16(a[1], Bf[1][nt], c1, 0, 0, 0);
                c2 = __builtin_amdgcn_mfma_f32_16x16x32_bf16(a[3], Bf[3][nt], c2, 0, 0, 0);
                cres[nt] = c1[0] + c2[0];
            }

            // ---- update (all C rows equal; cres = (u_pub*E)[16nt+l15]) ----
#pragma unroll
            for (int nt = 0; nt < 8; ++nt) {
                const float cand = isB ? cres[nt] : ef[nt] * cres[nt];
                x[nt] = mt_c ? cand : x[nt];
            }

            // rotate pipelined state
            mt_c = mt_n;
#pragma unroll
            for (int nt = 0; nt < 8; ++nt) ef[nt] = efn[nt];

            if (h == 7) {
                // wave-local exact power-of-2 rescale (identical on lanes)
                float s = 0.f;
#pragma unroll
                for (int nt = 0; nt < 8; ++nt) s += x[nt];
                s += swzf<0x041F>(s);  // xor 1
                s += swzf<0x081F>(s);  // xor 2
                s += swzf<0x101F>(s);  // xor 4
                s += swzf<0x201F>(s);  // xor 8
                int ex;
                frexpf(s, &ex);
#pragma unroll
                for (int nt = 0; nt < 8; ++nt) x[nt] = ldexpf(x[nt], -ex);
                eacc += ex;
            }
        }
    }

    // ---- export final vector + exponent ----
    float* vout = ws + (isB ? NB * LL : 0) + b * LL;
    if (g == 0) {
#pragma unroll
        for (int nt = 0; nt < 8; ++nt) vout[16 * nt + l15] = x[nt];
    }
    if (l == 0) ws[2 * NB * LL + isB * NB + b] = (float)eacc;

    // ---- numerator (gold path, fp32 exact) on the bwd blocks ----
    if (isB) {
        const int* lb = labels + b * SS;
        float term = 0.f;
        int cnt = 0;
#pragma unroll
        for (int rr = 0; rr < 8; ++rr) {
            const int tt = l + 64 * rr;
            int lc = lb[tt];
            if ((unsigned)lc >= LL) lc = 0;
            const int m = mk[tt];
            cnt += (m != 0);
            if (tt == 0) {
                term += start_t[lc] + fb[lc];
            } else if (m) {
                int lp = lb[tt - 1];
                if ((unsigned)lp >= LL) lp = 0;
                term += trans[lp * LL + lc] + fb[(size_t)tt * LL + lc];
            }
        }
#pragma unroll
        for (int o = 1; o < 64; o <<= 1) {
            term += __shfl_xor(term, o);
            cnt += __shfl_xor(cnt, o);
        }
        if (l == 0) {
            int sl = cnt - 1;
            sl = sl < 0 ? 0 : (sl >= SS ? SS - 1 : sl);
            int lt = lb[sl];
            if ((unsigned)lt >= LL) lt = 0;
            ws[2 * NB * LL + 2 * NB + b] = term + end_t[lt];
        }
    }
}

// Combine: Z = sum_i alpha_255[i]*beta_255[i] * 2^(eF+eB); loss reduce.
__global__ __launch_bounds__(256) void crf_final_kernel(
    const float* __restrict__ ws, const float* __restrict__ conf,
    float* __restrict__ out)
{
    const int tid = threadIdx.x;  // = batch index
    const float* av = ws;
    const float* bv = ws + NB * LL;
    const float* eFa = ws + 2 * NB * LL;
    const float* eBa = eFa + NB;
    const float* ln = eBa + NB;

    const float4* a4 = (const float4*)(av + tid * LL);
    const float4* b4 = (const float4*)(bv + tid * LL);
    float dot = 0.f;
#pragma unroll 8
    for (int k = 0; k < 32; ++k) {
        float4 a = a4[k], bb = b4[k];
        dot += a.x * bb.x + a.y * bb.y + a.z * bb.z + a.w * bb.w;
    }
    float logZ = logf(dot) + 0.69314718055994531f * (eFa[tid] + eBa[tid]);
    float loss = (logZ - ln[tid]) * conf[tid] * (1.0f / NB);

#pragma unroll
    for (int o = 1; o < 64; o <<= 1) loss += __shfl_xor(loss, o);
    __shared__ float red[4];
    if ((tid & 63) == 0) red[tid >> 6] = loss;
    __syncthreads();
    if (tid == 0) out[0] = red[0] + red[1] + red[2] + red[3];
}

extern "C" void kernel_launch(void* const* d_in, const int* in_sizes, int n_in,
                              void* d_out, int out_size, void* d_ws, size_t ws_size,
                              hipStream_t stream) {
    const float* feats  = (const float*)d_in[0];
    const float* startt = (const float*)d_in[1];
    const float* endt   = (const float*)d_in[2];
    const float* trans  = (const float*)d_in[3];
    const float* conf   = (const float*)d_in[4];
    const int*   mask   = (const int*)d_in[5];
    const int*   labels = (const int*)d_in[6];
    float* out = (float*)d_out;
    float* ws = (float*)d_ws;  // 2*256*128 + 3*256 floats ~ 266 KB

    hipLaunchKernelGGL(crf_chain_kernel, dim3(2 * NB), dim3(64), 0, stream,
                       feats, startt, endt, trans, mask, labels, ws);
    hipLaunchKernelGGL(crf_final_kernel, dim3(1), dim3(256), 0, stream,
                       ws, conf, out);
}